// Round 1
// baseline (530.888 us; speedup 1.0000x reference)
//
#include <hip/hip_runtime.h>
#include <hip/hip_bf16.h>

#define N_ 16384
#define D_ 512
#define BM 128
#define BN 128
#define BK 64
#define NBLK (N_ / BM)  // 128 blocks per dim

typedef __attribute__((ext_vector_type(8))) __bf16 bf16x8;
typedef __attribute__((ext_vector_type(4))) float f32x4;

#define GLDS(gptr, lptr)                                                              \
  __builtin_amdgcn_global_load_lds((const __attribute__((address_space(1))) void*)(gptr), \
                                   (__attribute__((address_space(3))) void*)(lptr), 16, 0, 0)

__device__ inline unsigned short f2bf(float f) {
  __hip_bfloat16 h = __float2bfloat16(f);
  return *reinterpret_cast<unsigned short*>(&h);
}

// ---------------- fp32 -> bf16 convert (vectorized) ----------------
__global__ void cvt_bf16_kernel(const float* __restrict__ src,
                                unsigned short* __restrict__ dst, long n) {
  long i = ((long)blockIdx.x * blockDim.x + threadIdx.x) * 8;
  const long stride = (long)gridDim.x * blockDim.x * 8;
  typedef __attribute__((ext_vector_type(8))) unsigned short us8;
  for (; i < n; i += stride) {
    const float4* s = (const float4*)(src + i);
    float4 f0 = s[0], f1 = s[1];
    us8 v;
    v[0] = f2bf(f0.x); v[1] = f2bf(f0.y); v[2] = f2bf(f0.z); v[3] = f2bf(f0.w);
    v[4] = f2bf(f1.x); v[5] = f2bf(f1.y); v[6] = f2bf(f1.z); v[7] = f2bf(f1.w);
    *(us8*)(dst + i) = v;
  }
}

// ---------------- fused GEMM + per-tile row/col online-LSE partials ----------------
__global__ __launch_bounds__(256, 3)
void gemm_lse_kernel(const unsigned short* __restrict__ A,   // img bf16 [N][D]
                     const unsigned short* __restrict__ B,   // txt bf16 [N][D]
                     const float* __restrict__ scale_p,
                     float2* __restrict__ rowMS,  // [NBLK(colblk)][N] (max, sumexp)
                     float2* __restrict__ colMS,  // [NBLK(rowblk)][N]
                     float* __restrict__ diag) {
  __shared__ unsigned short As[BM][BK];
  __shared__ unsigned short Bs[BN][BK];
  __shared__ float rowbuf[2][BM][2];
  __shared__ float colbuf[2][BN][2];

  const int t = threadIdx.x;
  const int l = t & 63;
  const int wid = t >> 6;
  const int wr = wid >> 1;   // wave row (0..1), wave tile 64x64
  const int wc = wid & 1;    // wave col

  // XCD-aware swizzle (nwg = 16384, divisible by 8 -> bijective)
  int id = blockIdx.x;
  id = (id & 7) * (NBLK * NBLK / 8) + (id >> 3);
  const int br = id / NBLK;
  const int bc = id % NBLK;

  // staging decomposition: thread t loads 16B at row (c*32 + t>>3), col (t&7)*8
  const int srow = t >> 3;
  const int scol = (t & 7) * 8;

  f32x4 acc[4][4];
#pragma unroll
  for (int m = 0; m < 4; ++m)
#pragma unroll
    for (int n = 0; n < 4; ++n) acc[m][n] = (f32x4)0.0f;

  const unsigned short* aBase = A + (size_t)(br * BM + srow) * D_ + scol;
  const unsigned short* bBase = B + (size_t)(bc * BN + srow) * D_ + scol;
  char* asBase = (char*)&As[0][0] + t * 16;
  char* bsBase = (char*)&Bs[0][0] + t * 16;

  for (int kt = 0; kt < D_ / BK; ++kt) {
    const int k0 = kt * BK;
#pragma unroll
    for (int c = 0; c < 4; ++c) GLDS(aBase + k0 + c * 32 * D_, asBase + c * 4096);
#pragma unroll
    for (int c = 0; c < 4; ++c) GLDS(bBase + k0 + c * 32 * D_, bsBase + c * 4096);
    __syncthreads();  // compiler drains vmcnt before barrier -> tile ready
#pragma unroll
    for (int kk = 0; kk < 2; ++kk) {
      const int krd = kk * 32 + (l >> 4) * 8;
      bf16x8 af[4], bfv[4];
#pragma unroll
      for (int m = 0; m < 4; ++m)
        af[m] = *(const bf16x8*)&As[wr * 64 + m * 16 + (l & 15)][krd];
#pragma unroll
      for (int n = 0; n < 4; ++n)
        bfv[n] = *(const bf16x8*)&Bs[wc * 64 + n * 16 + (l & 15)][krd];
#pragma unroll
      for (int m = 0; m < 4; ++m)
#pragma unroll
        for (int n = 0; n < 4; ++n)
          acc[m][n] = __builtin_amdgcn_mfma_f32_16x16x32_bf16(af[m], bfv[n], acc[m][n], 0, 0, 0);
    }
    __syncthreads();
  }

  // ---- epilogue: scale, diag, row/col online-LSE partials ----
  const float scale = scale_p[0];
#pragma unroll
  for (int m = 0; m < 4; ++m)
#pragma unroll
    for (int n = 0; n < 4; ++n)
#pragma unroll
      for (int r = 0; r < 4; ++r) acc[m][n][r] *= scale;

  // C/D layout (m89-verified): col = l&15, row = (l>>4)*4 + r  (within 16x16 frag)
  if (br == bc && wr == wc) {
#pragma unroll
    for (int m = 0; m < 4; ++m)
#pragma unroll
      for (int r = 0; r < 4; ++r)
        if ((l & 15) == ((l >> 4) * 4 + r))
          diag[br * BM + wr * 64 + m * 16 + (l & 15)] = acc[m][m][r];
  }

  // ROW pass: row = wr*64 + m*16 + (l>>4)*4 + r ; its 64 cols live in {n} x {lanes same l>>4}
#pragma unroll
  for (int m = 0; m < 4; ++m) {
#pragma unroll
    for (int r = 0; r < 4; ++r) {
      float mx = fmaxf(fmaxf(acc[m][0][r], acc[m][1][r]), fmaxf(acc[m][2][r], acc[m][3][r]));
#pragma unroll
      for (int off = 1; off < 16; off <<= 1) mx = fmaxf(mx, __shfl_xor(mx, off, 64));
      float s = 0.f;
#pragma unroll
      for (int n = 0; n < 4; ++n) s += __expf(acc[m][n][r] - mx);
#pragma unroll
      for (int off = 1; off < 16; off <<= 1) s += __shfl_xor(s, off, 64);
      if ((l & 15) == 0) {
        int row = wr * 64 + m * 16 + (l >> 4) * 4 + r;
        rowbuf[wc][row][0] = mx;
        rowbuf[wc][row][1] = s;
      }
    }
  }

  // COL pass: col = wc*64 + n*16 + (l&15); its 64 rows live in {m,r} x {lane>>4 groups}
#pragma unroll
  for (int n = 0; n < 4; ++n) {
    float mx = -1e30f;
#pragma unroll
    for (int m = 0; m < 4; ++m)
#pragma unroll
      for (int r = 0; r < 4; ++r) mx = fmaxf(mx, acc[m][n][r]);
    mx = fmaxf(mx, __shfl_xor(mx, 16, 64));
    mx = fmaxf(mx, __shfl_xor(mx, 32, 64));
    float s = 0.f;
#pragma unroll
    for (int m = 0; m < 4; ++m)
#pragma unroll
      for (int r = 0; r < 4; ++r) s += __expf(acc[m][n][r] - mx);
    s += __shfl_xor(s, 16, 64);
    s += __shfl_xor(s, 32, 64);
    if ((l >> 4) == 0) {
      int col = wc * 64 + n * 16 + l;
      colbuf[wr][col][0] = mx;
      colbuf[wr][col][1] = s;
    }
  }
  __syncthreads();

  // merge the two wave-halves, write partials (coalesced float2)
  if (t < BM) {
    float m0 = rowbuf[0][t][0], s0 = rowbuf[0][t][1];
    float m1 = rowbuf[1][t][0], s1 = rowbuf[1][t][1];
    float mm = fmaxf(m0, m1);
    float ss = s0 * __expf(m0 - mm) + s1 * __expf(m1 - mm);
    rowMS[(size_t)bc * N_ + br * BM + t] = make_float2(mm, ss);
  } else {
    int c = t - BM;
    float m0 = colbuf[0][c][0], s0 = colbuf[0][c][1];
    float m1 = colbuf[1][c][0], s1 = colbuf[1][c][1];
    float mm = fmaxf(m0, m1);
    float ss = s0 * __expf(m0 - mm) + s1 * __expf(m1 - mm);
    colMS[(size_t)br * N_ + bc * BN + c] = make_float2(mm, ss);
  }
}

// ---------------- merge partials -> per-row/col LSE -> partial sums ----------------
__global__ void reduce1_kernel(const float2* __restrict__ rowMS,
                               const float2* __restrict__ colMS,
                               const float* __restrict__ diag,
                               float* __restrict__ partials) {
  const int tid = blockIdx.x * blockDim.x + threadIdx.x;  // 0..32767
  float m = -1e30f, s = 0.f;
  if (tid < N_) {
    const int r = tid;
    for (int cb = 0; cb < NBLK; ++cb) {
      float2 p = rowMS[(size_t)cb * N_ + r];
      float nm = fmaxf(m, p.x);
      s = s * __expf(m - nm) + p.y * __expf(p.x - nm);
      m = nm;
    }
    m = m + logf(s) - diag[r];
  } else {
    const int c = tid - N_;
    for (int rb = 0; rb < NBLK; ++rb) {
      float2 p = colMS[(size_t)rb * N_ + c];
      float nm = fmaxf(m, p.x);
      s = s * __expf(m - nm) + p.y * __expf(p.x - nm);
      m = nm;
    }
    m = m + logf(s) - diag[c];
  }
  float val = m;
#pragma unroll
  for (int off = 1; off < 64; off <<= 1) val += __shfl_xor(val, off, 64);
  __shared__ float red[4];
  if ((threadIdx.x & 63) == 0) red[threadIdx.x >> 6] = val;
  __syncthreads();
  if (threadIdx.x == 0) partials[blockIdx.x] = red[0] + red[1] + red[2] + red[3];
}

__global__ void reduce2_kernel(const float* __restrict__ partials, float* __restrict__ out) {
  const int t = threadIdx.x;  // 64 threads
  float v = partials[t] + partials[t + 64];
#pragma unroll
  for (int off = 1; off < 64; off <<= 1) v += __shfl_xor(v, off, 64);
  if (t == 0) out[0] = v * (1.0f / (2.0f * (float)N_));
}

extern "C" void kernel_launch(void* const* d_in, const int* in_sizes, int n_in,
                              void* d_out, int out_size, void* d_ws, size_t ws_size,
                              hipStream_t stream) {
  const float* img = (const float*)d_in[0];
  const float* txt = (const float*)d_in[1];
  const float* scale = (const float*)d_in[2];
  float* out = (float*)d_out;

  char* ws = (char*)d_ws;
  size_t off = 0;
  unsigned short* imgB = (unsigned short*)(ws + off); off += (size_t)N_ * D_ * 2;
  unsigned short* txtB = (unsigned short*)(ws + off); off += (size_t)N_ * D_ * 2;
  float2* rowMS = (float2*)(ws + off); off += (size_t)NBLK * N_ * sizeof(float2);
  float2* colMS = (float2*)(ws + off); off += (size_t)NBLK * N_ * sizeof(float2);
  float* diag = (float*)(ws + off); off += (size_t)N_ * sizeof(float);
  float* partials = (float*)(ws + off); off += 128 * sizeof(float);
  (void)ws_size; (void)in_sizes; (void)n_in; (void)out_size;

  cvt_bf16_kernel<<<1024, 256, 0, stream>>>(img, imgB, (long)N_ * D_);
  cvt_bf16_kernel<<<1024, 256, 0, stream>>>(txt, txtB, (long)N_ * D_);
  gemm_lse_kernel<<<NBLK * NBLK, 256, 0, stream>>>(imgB, txtB, scale, rowMS, colMS, diag);
  reduce1_kernel<<<(2 * N_) / 256, 256, 0, stream>>>(rowMS, colMS, diag, partials);
  reduce2_kernel<<<1, 64, 0, stream>>>(partials, out);
}

// Round 2
// 408.672 us; speedup vs baseline: 1.2991x; 1.2991x over previous
//
#include <hip/hip_runtime.h>
#include <hip/hip_bf16.h>

#define N_ 16384
#define D_ 512
#define BM 128
#define BN 128
#define BK 64
#define NBLK (N_ / BM)  // 128 blocks per dim

typedef __attribute__((ext_vector_type(8))) __bf16 bf16x8;
typedef __attribute__((ext_vector_type(4))) float f32x4;

#define GLDS(gptr, lptr)                                                              \
  __builtin_amdgcn_global_load_lds((const __attribute__((address_space(1))) void*)(gptr), \
                                   (__attribute__((address_space(3))) void*)(lptr), 16, 0, 0)

__device__ inline unsigned short f2bf(float f) {
  __hip_bfloat16 h = __float2bfloat16(f);
  return *reinterpret_cast<unsigned short*>(&h);
}

// ---------------- fp32 -> bf16 convert (vectorized), optional scale fold ----------------
__global__ void cvt_bf16_kernel(const float* __restrict__ src,
                                unsigned short* __restrict__ dst, long n,
                                const float* __restrict__ scale_p) {
  const float s = scale_p ? scale_p[0] : 1.0f;
  long i = ((long)blockIdx.x * blockDim.x + threadIdx.x) * 8;
  const long stride = (long)gridDim.x * blockDim.x * 8;
  typedef __attribute__((ext_vector_type(8))) unsigned short us8;
  for (; i < n; i += stride) {
    const float4* sp = (const float4*)(src + i);
    float4 f0 = sp[0], f1 = sp[1];
    us8 v;
    v[0] = f2bf(f0.x * s); v[1] = f2bf(f0.y * s); v[2] = f2bf(f0.z * s); v[3] = f2bf(f0.w * s);
    v[4] = f2bf(f1.x * s); v[5] = f2bf(f1.y * s); v[6] = f2bf(f1.z * s); v[7] = f2bf(f1.w * s);
    *(us8*)(dst + i) = v;
  }
}

// ---------------- fused GEMM + per-tile row/col online-LSE partials ----------------
// LDS layout is st-16-style XOR-swizzled: byte (row*128 + Z) holds global data
// for (row, Z ^ ((row&7)<<4)). global_load_lds dest stays LINEAR (rule #21);
// the swizzle is applied by permuting the per-lane GLOBAL source column and
// XOR-ing the ds_read byte address. 16-way bank conflict -> conflict-free.
__global__ __launch_bounds__(256, 4)
void gemm_lse_kernel(const unsigned short* __restrict__ A,   // scale*img bf16 [N][D]
                     const unsigned short* __restrict__ B,   // txt bf16 [N][D]
                     float2* __restrict__ rowMS,  // [NBLK(colblk)][N] (max, sumexp)
                     float2* __restrict__ colMS,  // [NBLK(rowblk)][N]
                     float* __restrict__ diag) {
  __shared__ unsigned short As[BM][BK];
  __shared__ unsigned short Bs[BN][BK];
  __shared__ float rowbuf[2][BM][2];
  __shared__ float colbuf[2][BN][2];

  const int t = threadIdx.x;
  const int l = t & 63;
  const int wid = t >> 6;
  const int wr = wid >> 1;   // wave row (0..1), wave tile 64x64
  const int wc = wid & 1;    // wave col

  // XCD-aware swizzle (nwg = 16384, divisible by 8 -> bijective)
  int id = blockIdx.x;
  id = (id & 7) * (NBLK * NBLK / 8) + (id >> 3);
  const int br = id / NBLK;
  const int bc = id % NBLK;

  // staging: thread t stages 16B to LINEAR LDS byte t*16 (+ c*4096).
  // row = c*32 + (t>>3); source col is the inverse-swizzled position.
  const int srow = t >> 3;
  const int scol = (((t & 7) ^ (srow & 7)) << 3);  // elements

  f32x4 acc[4][4];
#pragma unroll
  for (int m = 0; m < 4; ++m)
#pragma unroll
    for (int n = 0; n < 4; ++n) acc[m][n] = (f32x4)0.0f;

  const unsigned short* aBase = A + (size_t)(br * BM + srow) * D_ + scol;
  const unsigned short* bBase = B + (size_t)(bc * BN + srow) * D_ + scol;
  char* asBase = (char*)&As[0][0] + t * 16;
  char* bsBase = (char*)&Bs[0][0] + t * 16;

  const int swz = (l & 7) << 4;  // ds_read byte-XOR: ((row&7)<<4), row&7 == l&7

  for (int kt = 0; kt < D_ / BK; ++kt) {
    const int k0 = kt * BK;
#pragma unroll
    for (int c = 0; c < 4; ++c) GLDS(aBase + k0 + c * 32 * D_, asBase + c * 4096);
#pragma unroll
    for (int c = 0; c < 4; ++c) GLDS(bBase + k0 + c * 32 * D_, bsBase + c * 4096);
    __syncthreads();  // compiler drains vmcnt before barrier -> tile ready
#pragma unroll
    for (int kk = 0; kk < 2; ++kk) {
      const int cb = (kk * 64 + (l >> 4) * 16);  // byte-in-row pre-swizzle
      bf16x8 af[4], bfv[4];
#pragma unroll
      for (int m = 0; m < 4; ++m)
        af[m] = *(const bf16x8*)((const char*)&As[0][0] +
                                 (wr * 64 + m * 16 + (l & 15)) * 128 + (cb ^ swz));
#pragma unroll
      for (int n = 0; n < 4; ++n)
        bfv[n] = *(const bf16x8*)((const char*)&Bs[0][0] +
                                  (wc * 64 + n * 16 + (l & 15)) * 128 + (cb ^ swz));
#pragma unroll
      for (int m = 0; m < 4; ++m)
#pragma unroll
        for (int n = 0; n < 4; ++n)
          acc[m][n] = __builtin_amdgcn_mfma_f32_16x16x32_bf16(af[m], bfv[n], acc[m][n], 0, 0, 0);
    }
    __syncthreads();
  }

  // ---- epilogue: diag, row/col online-LSE partials (scale pre-folded into A) ----
  // C/D layout (m89-verified): col = l&15, row = (l>>4)*4 + r  (within 16x16 frag)
  if (br == bc && wr == wc) {
#pragma unroll
    for (int m = 0; m < 4; ++m)
#pragma unroll
      for (int r = 0; r < 4; ++r)
        if ((l & 15) == ((l >> 4) * 4 + r))
          diag[br * BM + wr * 64 + m * 16 + (l & 15)] = acc[m][m][r];
  }

  // ROW pass: row = wr*64 + m*16 + (l>>4)*4 + r ; its 64 cols live in {n} x {lanes same l>>4}
#pragma unroll
  for (int m = 0; m < 4; ++m) {
#pragma unroll
    for (int r = 0; r < 4; ++r) {
      float mx = fmaxf(fmaxf(acc[m][0][r], acc[m][1][r]), fmaxf(acc[m][2][r], acc[m][3][r]));
#pragma unroll
      for (int off = 1; off < 16; off <<= 1) mx = fmaxf(mx, __shfl_xor(mx, off, 64));
      float s = 0.f;
#pragma unroll
      for (int n = 0; n < 4; ++n) s += __expf(acc[m][n][r] - mx);
#pragma unroll
      for (int off = 1; off < 16; off <<= 1) s += __shfl_xor(s, off, 64);
      if ((l & 15) == 0) {
        int row = wr * 64 + m * 16 + (l >> 4) * 4 + r;
        rowbuf[wc][row][0] = mx;
        rowbuf[wc][row][1] = s;
      }
    }
  }

  // COL pass: col = wc*64 + n*16 + (l&15); its 64 rows live in {m,r} x {lane>>4 groups}
#pragma unroll
  for (int n = 0; n < 4; ++n) {
    float mx = -1e30f;
#pragma unroll
    for (int m = 0; m < 4; ++m)
#pragma unroll
      for (int r = 0; r < 4; ++r) mx = fmaxf(mx, acc[m][n][r]);
    mx = fmaxf(mx, __shfl_xor(mx, 16, 64));
    mx = fmaxf(mx, __shfl_xor(mx, 32, 64));
    float s = 0.f;
#pragma unroll
    for (int m = 0; m < 4; ++m)
#pragma unroll
      for (int r = 0; r < 4; ++r) s += __expf(acc[m][n][r] - mx);
    s += __shfl_xor(s, 16, 64);
    s += __shfl_xor(s, 32, 64);
    if ((l >> 4) == 0) {
      int col = wc * 64 + n * 16 + l;
      colbuf[wr][col][0] = mx;
      colbuf[wr][col][1] = s;
    }
  }
  __syncthreads();

  // merge the two wave-halves, write partials (coalesced float2)
  if (t < BM) {
    float m0 = rowbuf[0][t][0], s0 = rowbuf[0][t][1];
    float m1 = rowbuf[1][t][0], s1 = rowbuf[1][t][1];
    float mm = fmaxf(m0, m1);
    float ss = s0 * __expf(m0 - mm) + s1 * __expf(m1 - mm);
    rowMS[(size_t)bc * N_ + br * BM + t] = make_float2(mm, ss);
  } else {
    int c = t - BM;
    float m0 = colbuf[0][c][0], s0 = colbuf[0][c][1];
    float m1 = colbuf[1][c][0], s1 = colbuf[1][c][1];
    float mm = fmaxf(m0, m1);
    float ss = s0 * __expf(m0 - mm) + s1 * __expf(m1 - mm);
    colMS[(size_t)br * N_ + bc * BN + c] = make_float2(mm, ss);
  }
}

// ---------------- merge partials -> per-row/col LSE -> partial sums ----------------
__global__ void reduce1_kernel(const float2* __restrict__ rowMS,
                               const float2* __restrict__ colMS,
                               const float* __restrict__ diag,
                               float* __restrict__ partials) {
  const int tid = blockIdx.x * blockDim.x + threadIdx.x;  // 0..32767
  float m = -1e30f, s = 0.f;
  if (tid < N_) {
    const int r = tid;
    for (int cb = 0; cb < NBLK; ++cb) {
      float2 p = rowMS[(size_t)cb * N_ + r];
      float nm = fmaxf(m, p.x);
      s = s * __expf(m - nm) + p.y * __expf(p.x - nm);
      m = nm;
    }
    m = m + logf(s) - diag[r];
  } else {
    const int c = tid - N_;
    for (int rb = 0; rb < NBLK; ++rb) {
      float2 p = colMS[(size_t)rb * N_ + c];
      float nm = fmaxf(m, p.x);
      s = s * __expf(m - nm) + p.y * __expf(p.x - nm);
      m = nm;
    }
    m = m + logf(s) - diag[c];
  }
  float val = m;
#pragma unroll
  for (int off = 1; off < 64; off <<= 1) val += __shfl_xor(val, off, 64);
  __shared__ float red[4];
  if ((threadIdx.x & 63) == 0) red[threadIdx.x >> 6] = val;
  __syncthreads();
  if (threadIdx.x == 0) partials[blockIdx.x] = red[0] + red[1] + red[2] + red[3];
}

__global__ void reduce2_kernel(const float* __restrict__ partials, float* __restrict__ out) {
  const int t = threadIdx.x;  // 64 threads
  float v = partials[t] + partials[t + 64];
#pragma unroll
  for (int off = 1; off < 64; off <<= 1) v += __shfl_xor(v, off, 64);
  if (t == 0) out[0] = v * (1.0f / (2.0f * (float)N_));
}

extern "C" void kernel_launch(void* const* d_in, const int* in_sizes, int n_in,
                              void* d_out, int out_size, void* d_ws, size_t ws_size,
                              hipStream_t stream) {
  const float* img = (const float*)d_in[0];
  const float* txt = (const float*)d_in[1];
  const float* scale = (const float*)d_in[2];
  float* out = (float*)d_out;

  char* ws = (char*)d_ws;
  size_t off = 0;
  unsigned short* imgB = (unsigned short*)(ws + off); off += (size_t)N_ * D_ * 2;
  unsigned short* txtB = (unsigned short*)(ws + off); off += (size_t)N_ * D_ * 2;
  float2* rowMS = (float2*)(ws + off); off += (size_t)NBLK * N_ * sizeof(float2);
  float2* colMS = (float2*)(ws + off); off += (size_t)NBLK * N_ * sizeof(float2);
  float* diag = (float*)(ws + off); off += (size_t)N_ * sizeof(float);
  float* partials = (float*)(ws + off); off += 128 * sizeof(float);
  (void)ws_size; (void)in_sizes; (void)n_in; (void)out_size;

  cvt_bf16_kernel<<<1024, 256, 0, stream>>>(img, imgB, (long)N_ * D_, scale);
  cvt_bf16_kernel<<<1024, 256, 0, stream>>>(txt, txtB, (long)N_ * D_, nullptr);
  gemm_lse_kernel<<<NBLK * NBLK, 256, 0, stream>>>(imgB, txtB, rowMS, colMS, diag);
  reduce1_kernel<<<(2 * N_) / 256, 256, 0, stream>>>(rowMS, colMS, diag, partials);
  reduce2_kernel<<<1, 64, 0, stream>>>(partials, out);
}